// Round 9
// baseline (1013.606 us; speedup 1.0000x reference)
//
#include <hip/hip_runtime.h>

// Problem dims (LRNetLinear): out = B x O, x = B x I, weights O x I
#define I_DIM 4096
#define O_DIM 4096
#define B_DIM 4096

typedef _Float16 f16;
typedef __attribute__((ext_vector_type(4))) _Float16 f16x4;
typedef __attribute__((ext_vector_type(8))) _Float16 f16x8;
typedef __attribute__((ext_vector_type(4))) float f32x4;
typedef __attribute__((ext_vector_type(16))) float f32x16;

struct f16pair { f16 m, v; };

// ---------------------------------------------------------------------------
// Weight transform: 3-way softmax stats -> (w_mean, w_var) in fp16
// ---------------------------------------------------------------------------
__device__ inline f16pair lr_wmv(float tn, float tp, float s) {
    float m = fmaxf(fmaxf(tn, tp), 0.0f);
    float en = __expf(tn - m);
    float ez = __expf(-m);
    float ep = __expf(tp - m);
    float inv = __builtin_amdgcn_rcpf(en + ez + ep);
    float pn = en * inv, pp = ep * inv;
    float d = pp - pn;
    f16pair r;
    r.m = (f16)(d * s);
    r.v = (f16)((pp + pn - d * d) * (s * s));
    return r;
}

// ---------------------------------------------------------------------------
// Fused prep — unchanged from round 8 (grid-stride, granule-coalesced).
// ---------------------------------------------------------------------------
__global__ __launch_bounds__(256)
void prep_all(const float4* __restrict__ x, f16x4* __restrict__ xb4,
              const float4* __restrict__ tn4, const float4* __restrict__ tp4,
              const float4* __restrict__ sc4,
              f16x4* __restrict__ wm4, f16x4* __restrict__ wv4) {
    const int G = (int)((size_t)O_DIM * I_DIM / 4);   // 4,194,304 granules
    const int nt = gridDim.x * blockDim.x;
    const int t0 = blockIdx.x * blockDim.x + threadIdx.x;

    for (int g = t0; g < G; g += nt) {
        float4 a = x[g];
        f16x4 o;
        o[0] = (f16)a.x; o[1] = (f16)a.y; o[2] = (f16)a.z; o[3] = (f16)a.w;
        xb4[g] = o;
    }
    for (int g = t0; g < G; g += nt) {
        float4 a = tn4[g], b = tp4[g], s = sc4[g];
        f16x4 om, ov;
        f16pair p;
        p = lr_wmv(a.x, b.x, s.x); om[0] = p.m; ov[0] = p.v;
        p = lr_wmv(a.y, b.y, s.y); om[1] = p.m; ov[1] = p.v;
        p = lr_wmv(a.z, b.z, s.z); om[2] = p.m; ov[2] = p.v;
        p = lr_wmv(a.w, b.w, s.w); om[3] = p.m; ov[3] = p.v;
        wm4[g] = om;
        wv4[g] = ov;
    }
}

// ---------------------------------------------------------------------------
// Fused dual GEMM — ROUND-9: 16x16x32 -> 32x32x16 MFMA conversion.
//   Mechanism: ubench 2382 vs 2075 TF (-15% matrix-pipe cycles) and HALF the
//   MFMA instruction count per phase (16 -> 8), doubling the issue slack the
//   round-7 split-cluster interleave exploits. Register-neutral (acc =
//   2x2x2 f32x16 = 128 regs, frag buffers same bytes). LDS tile layout,
//   staging, swizzle, phase/barrier/vmcnt schedule BYTE-IDENTICAL to the
//   verified 249-255us kernel; only fragment reads, MFMA shape, and the
//   epilogue C/D mapping change.
//   Fragment geometry (32x32x16): A row = lane&31, k = (lane>>5)*8; B col =
//   lane&31, same k split. With 64B LDS rows and slot = (2ks+hi)^((r5>>1)&3),
//   the 64 16B chunks of each ds_read_b128 spread exactly 8 per bank-quad
//   (= data-volume floor, same as the current 0-conflict pattern).
//   C/D: col = lane&31, row = (reg&3) + 8*(reg>>2) + 4*(lane>>5) [m74/m101].
// ---------------------------------------------------------------------------
#define BM 256
#define BN 128
#define BK 64

__device__ inline void gl_lds16(const f16* g, f16* l) {
    __builtin_amdgcn_global_load_lds(
        (const __attribute__((address_space(1))) unsigned int*)g,
        (__attribute__((address_space(3))) unsigned int*)l,
        16, 0, 0);
}

#define VM8 asm volatile("s_waitcnt vmcnt(8)")
#define VM6 asm volatile("s_waitcnt vmcnt(6)")
#define VM4 asm volatile("s_waitcnt vmcnt(4)")
#define VM0 asm volatile("s_waitcnt vmcnt(0)")
#define VMNONE (void)0

#define MFMA32(A_, B_, C_) __builtin_amdgcn_mfma_f32_32x32x16_f16((A_), (B_), (C_), 0, 0, 0)

__global__ __launch_bounds__(512, 2)
void fused_dual_gemm(const f16* __restrict__ Xb,
                     const f16* __restrict__ Wm, const f16* __restrict__ Wv,
                     const float* __restrict__ eps, float* __restrict__ out) {
    __shared__ f16 smem[65536];                // 128 KB
    // elem offsets: X(p,kh) = p*32768 + kh*8192            (256 rows x 32)
    //               Wm(p,kh) = 16384 + p*32768 + kh*8192   (128 rows x 32)
    //               Wv(p,kh) = Wm + 4096

    const int tid  = threadIdx.x;
    const int lane = tid & 63;
    const int wave = tid >> 6;

    const int bm = blockIdx.y * BM;
    const int bn = blockIdx.x * BN;

    // ---- staging source (per-lane pre-swizzled granule): chunk = 16 rows x 64B.
    const int srow = lane >> 2;
    const int scol = (((lane & 3) ^ ((lane >> 3) & 3)) << 3);   // elems
    const f16* gX = Xb + (size_t)(bm + 32 * wave + srow) * I_DIM + scol;
    const f16* gM = Wm + (size_t)(bn + 16 * wave + srow) * I_DIM + scol;
    const f16* gV = Wv + (size_t)(bn + 16 * wave + srow) * I_DIM + scol;
    f16* ldsX = smem + wave * 1024;            // + p*32768 + kh*8192 (+512 chunk 1)
    f16* ldsW = smem + 16384 + wave * 512;     // + p*32768 + kh*8192 (+4096 for Wv)

    // ---- fragment geometry (32x32x16): row/col = lane&31, k-granule = lane>>5
    const int r5 = lane & 31;
    const int hi = lane >> 5;
    const int e0 = ((hi ^ ((r5 >> 1) & 3)) << 3);   // swizzled base slot (elems)
    const int m0 = (wave >> 1) << 6;           // 4 M-waves: 0,64,128,192
    const int n0 = (wave & 1) << 6;            // 2 N-waves: 0,64

    f32x16 accM[2][2];
    f32x16 accV[2][2];
#pragma unroll
    for (int mi = 0; mi < 2; ++mi)
#pragma unroll
        for (int ni = 0; ni < 2; ++ni) {
#pragma unroll
            for (int j = 0; j < 16; ++j) { accM[mi][ni][j] = 0.0f; accV[mi][ni][j] = 0.0f; }
        }

    // fragment double-buffers (all statically indexed)
    // A layout: [0]=mi0 ks0, [1]=mi0 ks1, [2]=mi1 ks0, [3]=mi1 ks1
    // B layout: [0]=Bm ks0, [1]=Bv ks0, [2]=Bm ks1, [3]=Bv ks1
    f16x8 A0[4], A1[4], A2c[4], Ba[4], Bb[4];

#define STAGE_X(kelem, reg) do {                                               \
        gl_lds16(gX + (kelem),              ldsX + (reg));                     \
        gl_lds16(gX + (kelem) + 16 * I_DIM, ldsX + (reg) + 512);               \
    } while (0)
#define STAGE_W(kelem, reg) do {                                               \
        gl_lds16(gM + (kelem), ldsW + (reg));                                  \
        gl_lds16(gV + (kelem), ldsW + (reg) + 4096);                           \
    } while (0)

#define RD_A32(DST, RX) do {                                                   \
        DST[0] = *(const f16x8*)(smem + (RX) + (m0 +  0 + r5) * 32 + e0);      \
        DST[1] = *(const f16x8*)(smem + (RX) + (m0 +  0 + r5) * 32 + (e0 ^ 16)); \
        DST[2] = *(const f16x8*)(smem + (RX) + (m0 + 32 + r5) * 32 + e0);      \
        DST[3] = *(const f16x8*)(smem + (RX) + (m0 + 32 + r5) * 32 + (e0 ^ 16)); \
    } while (0)
#define RD_B32(DST, RW, NI) do {                                               \
        DST[0] = *(const f16x8*)(smem + (RW)        + (n0 + (NI)*32 + r5) * 32 + e0); \
        DST[1] = *(const f16x8*)(smem + (RW) + 4096 + (n0 + (NI)*32 + r5) * 32 + e0); \
        DST[2] = *(const f16x8*)(smem + (RW)        + (n0 + (NI)*32 + r5) * 32 + (e0 ^ 16)); \
        DST[3] = *(const f16x8*)(smem + (RW) + 4096 + (n0 + (NI)*32 + r5) * 32 + (e0 ^ 16)); \
    } while (0)

// 4 MFMAs, k-sub 0 (frag idx 0/2, B idx 0/1), acc column NI
#define MFMA4a(AC, BB, NI) do {                                                \
        accM[0][NI] = MFMA32(AC[0],  BB[0], accM[0][NI]);                      \
        accV[0][NI] = MFMA32(A2c[0], BB[1], accV[0][NI]);                      \
        accM[1][NI] = MFMA32(AC[2],  BB[0], accM[1][NI]);                      \
        accV[1][NI] = MFMA32(A2c[2], BB[1], accV[1][NI]);                      \
    } while (0)
// 4 MFMAs, k-sub 1 (frag idx 1/3, B idx 2/3)
#define MFMA4b(AC, BB, NI) do {                                                \
        accM[0][NI] = MFMA32(AC[1],  BB[2], accM[0][NI]);                      \
        accV[0][NI] = MFMA32(A2c[1], BB[3], accV[0][NI]);                      \
        accM[1][NI] = MFMA32(AC[3],  BB[2], accM[1][NI]);                      \
        accV[1][NI] = MFMA32(A2c[3], BB[3], accV[1][NI]);                      \
    } while (0)

#define A2C(AC) do {                                                           \
        _Pragma("unroll")                                                      \
        for (int j = 0; j < 4; ++j) A2c[j] = AC[j] * AC[j];                    \
    } while (0)

// even phase: STG first (async prefetch); ni=0 on AC,Ba; 4+4 MFMA with the
// 4 Bb ds_reads (ni=1, same kh) between the halves.
#define PH_EVEN(AC, RWcur, STG, VM) do {                                       \
        STG;                                                                   \
        A2C(AC);                                                               \
        __builtin_amdgcn_s_setprio(1);                                         \
        MFMA4a(AC, Ba, 0);                                                     \
        RD_B32(Bb, RWcur, 1);                                                  \
        MFMA4b(AC, Ba, 0);                                                     \
        __builtin_amdgcn_s_setprio(0);                                         \
        VM; __builtin_amdgcn_s_barrier();                                      \
    } while (0)
// odd phase: STG first; ni=1 on AC,Bb; RD_A between halves, RD_B after.
#define PH_ODD(AC, ANext, RXn, RWn, STG, VM) do {                              \
        STG;                                                                   \
        __builtin_amdgcn_s_setprio(1);                                         \
        MFMA4a(AC, Bb, 1);                                                     \
        RD_A32(ANext, RXn);                                                    \
        MFMA4b(AC, Bb, 1);                                                     \
        __builtin_amdgcn_s_setprio(0);                                         \
        RD_B32(Ba, RWn, 0);                                                    \
        VM; __builtin_amdgcn_s_barrier();                                      \
    } while (0)

    // ---- prologue: stage {X,W}(t0)k0, {X,W}(t0)k1, {X,W}(t1)k0 = 12 loads;
    // force the oldest 4 (tile0 kh0), then preload P0's fragments.
    STAGE_X(0, 0);      STAGE_W(0, 0);
    STAGE_X(32, 8192);  STAGE_W(32, 8192);
    STAGE_X(64, 32768); STAGE_W(64, 32768);
    VM8;
    __builtin_amdgcn_s_barrier();
    RD_A32(A0, 0);
    RD_B32(Ba, 16384, 0);

    // ---- main loop: 31 iterations x 2 K-tiles (tiles 0..61), prefetch 2 ahead.
    // Per phase, reads serve the NEXT phase; VM6 at even-phase ends publishes
    // each region exactly one barrier before its (shifted-early) read phase.
#pragma unroll 1
    for (int i = 0; i < 31; ++i) {
        const int kb = i * 128;
        PH_EVEN(A0, 16384,            STAGE_X(kb +  96, 40960), VM6);    // P0 t0k0 ni0
        PH_ODD (A0, A1, 8192, 24576,  STAGE_W(kb +  96, 40960), VMNONE); // P1 t0k0 ni1
        PH_EVEN(A1, 24576,            STAGE_X(kb + 128,     0), VM6);    // P2 t0k1 ni0
        PH_ODD (A1, A0, 32768, 49152, STAGE_W(kb + 128,     0), VMNONE); // P3 t0k1 ni1
        PH_EVEN(A0, 49152,            STAGE_X(kb + 160,  8192), VM6);    // P4 t1k0 ni0
        PH_ODD (A0, A1, 40960, 57344, STAGE_W(kb + 160,  8192), VMNONE); // P5 t1k0 ni1
        PH_EVEN(A1, 57344,            STAGE_X(kb + 192, 32768), VM6);    // P6 t1k1 ni0
        PH_ODD (A1, A0, 0, 16384,     STAGE_W(kb + 192, 32768), VMNONE); // P7 t1k1 ni1
    }

    // ---- tail: tiles 62,63. Only X/W(63,k1) still to issue; drain 6->4->0,
    // each VM placed one phase before the region's read (audited).
    PH_EVEN(A0, 16384,            STAGE_X(4064, 40960), VM6);    // TP0
    PH_ODD (A0, A1, 8192, 24576,  STAGE_W(4064, 40960), VMNONE); // TP1
    PH_EVEN(A1, 24576,            VMNONE, VM4);                  // TP2
    PH_ODD (A1, A0, 32768, 49152, VMNONE, VMNONE);               // TP3
    PH_EVEN(A0, 49152,            VMNONE, VM0);                  // TP4
    PH_ODD (A0, A1, 40960, 57344, VMNONE, VMNONE);               // TP5
    PH_EVEN(A1, 57344,            VMNONE, VMNONE);               // TP6
    MFMA4a(A1, Bb, 1);                                           // TP7 (no reads)
    MFMA4b(A1, Bb, 1);

    // ---- epilogue: C/D 32x32 layout col = lane&31, row = (reg&3)+8*(reg>>2)+4*hi
#pragma unroll
    for (int mi = 0; mi < 2; ++mi) {
#pragma unroll
        for (int ni = 0; ni < 2; ++ni) {
            const int gn  = bn + n0 + ni * 32 + r5;
            const int gmb = bm + m0 + mi * 32 + 4 * hi;
#pragma unroll
            for (int q = 0; q < 4; ++q) {
#pragma unroll
                for (int r = 0; r < 4; ++r) {
                    const int row = gmb + q * 8 + r;
                    const size_t off = (size_t)row * O_DIM + gn;
                    const float mu = accM[mi][ni][q * 4 + r];
                    const float vv = accV[mi][ni][q * 4 + r];
                    out[off] = fmaf(sqrtf(fmaxf(vv, 1e-8f)), eps[off], mu);
                }
            }
        }
    }
#undef PH_ODD
#undef PH_EVEN
#undef A2C
#undef MFMA4a
#undef MFMA4b
#undef RD_B32
#undef RD_A32
#undef STAGE_W
#undef STAGE_X
}

// ---------------------------------------------------------------------------
extern "C" void kernel_launch(void* const* d_in, const int* in_sizes, int n_in,
                              void* d_out, int out_size, void* d_ws, size_t ws_size,
                              hipStream_t stream) {
    const float* x   = (const float*)d_in[0];
    const float* tn  = (const float*)d_in[1];
    const float* tp  = (const float*)d_in[2];
    const float* sc  = (const float*)d_in[3];
    const float* eps = (const float*)d_in[4];
    float* out = (float*)d_out;

    const size_t NE = (size_t)O_DIM * I_DIM;   // 16.7M
    f16* xb = (f16*)d_ws;                      // 32 MB
    f16* wm = xb + NE;                         // 32 MB
    f16* wv = wm + NE;                         // 32 MB

    prep_all<<<2048, 256, 0, stream>>>(
        (const float4*)x, (f16x4*)xb,
        (const float4*)tn, (const float4*)tp, (const float4*)sc,
        (f16x4*)wm, (f16x4*)wv);

    dim3 grid(O_DIM / BN, B_DIM / BM);   // (32, 16)
    fused_dual_gemm<<<grid, 512, 0, stream>>>(
        (const f16*)xb, (const f16*)wm, (const f16*)wv, eps, out);
}